// Round 2
// baseline (1267.245 us; speedup 1.0000x reference)
//
#include <hip/hip_runtime.h>

#define T_TOK 8192
#define DDIM 1024
#define IDIM 2048
#define NEXP 8

typedef short bf16x8 __attribute__((ext_vector_type(8)));
typedef float f32x4 __attribute__((ext_vector_type(4)));

__device__ __forceinline__ unsigned short f2bf(float f) {
  union { float f; unsigned int u; } v; v.f = f;
  unsigned int r = v.u + 0x7fffu + ((v.u >> 16) & 1u);
  return (unsigned short)(r >> 16);
}
__device__ __forceinline__ float bf2f(unsigned short u) {
  union { unsigned int u; float f; } v; v.u = (unsigned int)u << 16;
  return v.f;
}

typedef const __attribute__((address_space(1))) void* gas_t;
typedef __attribute__((address_space(3))) void* las_t;
__device__ __forceinline__ void async_copy16(void* lds, const void* g) {
  __builtin_amdgcn_global_load_lds((gas_t)g, (las_t)lds, 16, 0, 0);
}

// ---------------- x -> bf16 ----------------
__global__ __launch_bounds__(256) void convert_kernel(const float* __restrict__ x,
                                                      ushort* __restrict__ xb, int n4) {
  int i = blockIdx.x * 256 + threadIdx.x;
  if (i >= n4) return;
  float4 v = ((const float4*)x)[i];
  ushort4 o;
  o.x = f2bf(v.x); o.y = f2bf(v.y); o.z = f2bf(v.z); o.w = f2bf(v.w);
  ((ushort4*)xb)[i] = o;
}

// ---------------- transpose + convert via LDS: src[e][R][C] f32 -> dst[e][C'][R] bf16 ----------------
__global__ __launch_bounds__(256) void tconv_kernel(
    const float* __restrict__ src, ushort* __restrict__ dst, int R, int C,
    int sel, int interleave, size_t srcEStride, size_t dstEStride) {
  __shared__ ushort lt[64 * 72];
  const int e = blockIdx.z;
  const float* s = src + (size_t)e * srcEStride;
  ushort* d = dst + (size_t)e * dstEStride;
  const int c0 = blockIdx.x * 64, r0 = blockIdx.y * 64;
  const int t = threadIdx.x;
  const int tr = t >> 2;
  const int tc = (t & 3) * 16;
  const float* sp = s + (size_t)(r0 + tr) * C + c0 + tc;
  float4 v0 = ((const float4*)sp)[0];
  float4 v1 = ((const float4*)sp)[1];
  float4 v2 = ((const float4*)sp)[2];
  float4 v3 = ((const float4*)sp)[3];
#pragma unroll
  for (int j = 0; j < 4; ++j) lt[(tc + j) * 72 + tr]      = f2bf(((const float*)&v0)[j]);
#pragma unroll
  for (int j = 0; j < 4; ++j) lt[(tc + 4 + j) * 72 + tr]  = f2bf(((const float*)&v1)[j]);
#pragma unroll
  for (int j = 0; j < 4; ++j) lt[(tc + 8 + j) * 72 + tr]  = f2bf(((const float*)&v2)[j]);
#pragma unroll
  for (int j = 0; j < 4; ++j) lt[(tc + 12 + j) * 72 + tr] = f2bf(((const float*)&v3)[j]);
  __syncthreads();
  const int cr = t >> 2;
  const int seg = (t & 3) * 16;
  const int ci = c0 + cr;
  const int drow = interleave ? ((ci >> 6) * 128 + sel * 64 + (ci & 63)) : ci;
  uint4 o0 = *(const uint4*)&lt[cr * 72 + seg];
  uint4 o1 = *(const uint4*)&lt[cr * 72 + seg + 8];
  ushort* dp = d + (size_t)drow * R + r0 + seg;
  *(uint4*)dp = o0;
  *(uint4*)(dp + 8) = o1;
}

// ---------------- router: top-2 + expert lists ----------------
__global__ __launch_bounds__(256) void router_kernel(
    const float* __restrict__ x, const float* __restrict__ rw, const float* __restrict__ rb,
    int* __restrict__ cnt, int* __restrict__ lists, float* __restrict__ wts,
    int* __restrict__ pexp) {
  const int token = blockIdx.x * 4 + (threadIdx.x >> 6);
  const int lane = threadIdx.x & 63;
  float acc[NEXP];
#pragma unroll
  for (int e = 0; e < NEXP; ++e) acc[e] = 0.f;
  const float* xr = x + (size_t)token * DDIM;
#pragma unroll
  for (int j = 0; j < DDIM / 64; ++j) {
    int d = j * 64 + lane;
    float xv = xr[d];
    const float4* w = (const float4*)(rw + d * NEXP);
    float4 w0 = w[0], w1 = w[1];
    acc[0] += xv * w0.x; acc[1] += xv * w0.y; acc[2] += xv * w0.z; acc[3] += xv * w0.w;
    acc[4] += xv * w1.x; acc[5] += xv * w1.y; acc[6] += xv * w1.z; acc[7] += xv * w1.w;
  }
#pragma unroll
  for (int e = 0; e < NEXP; ++e) {
    float v = acc[e];
    for (int off = 32; off > 0; off >>= 1) v += __shfl_xor(v, off, 64);
    acc[e] = v;
  }
  if (lane == 0) {
    float l[NEXP];
#pragma unroll
    for (int e = 0; e < NEXP; ++e) l[e] = acc[e] + rb[e];
    int i0 = 0; float b0 = l[0];
#pragma unroll
    for (int e = 1; e < NEXP; ++e) if (l[e] > b0) { b0 = l[e]; i0 = e; }
    int i1 = -1; float b1 = -3.0e38f;
#pragma unroll
    for (int e = 0; e < NEXP; ++e) if (e != i0 && l[e] > b1) { b1 = l[e]; i1 = e; }
    float e1 = expf(b1 - b0);
    float inv = 1.f / (1.f + e1);
    wts[token * 2 + 0] = inv;
    wts[token * 2 + 1] = e1 * inv;
    pexp[token * 2 + 0] = i0;
    pexp[token * 2 + 1] = i1;
    int s0 = atomicAdd(&cnt[i0], 1);
    lists[i0 * T_TOK + s0] = token * 2;
    int s1 = atomicAdd(&cnt[i1], 1);
    lists[i1 * T_TOK + s1] = token * 2 + 1;
  }
}

// ---------------- GEMM1: fused gate/up, 256x256 tile, BK=64, 8-phase (4/ K-tile) schedule ----------------
// 512 threads = 8 waves (2M x 4N). Per-wave output 128x64. LDS: A[2][256][64] | B[2][256][64] bf16 = 128 KB.
// K-tile t lives in dbuf (t&1). During tile t's 4 compute phases, tile t+1 is staged into the other
// dbuf (issued at phase 1, drained with vmcnt(0) at end of phase 4) -> HBM latency hides under ~4 phases
// of MFMA. Raw s_barrier (NOT __syncthreads) so the in-flight loads are never drained early.
__global__ __launch_bounds__(512, 2) void gemm1_kernel(
    const ushort* __restrict__ xb, const ushort* __restrict__ wcat,
    const float* __restrict__ gate_b, const float* __restrict__ up_b,
    const int* __restrict__ lists, const int* __restrict__ cnt,
    ushort* __restrict__ hbuf) {
  const int e = blockIdx.z;
  const int ce = cnt[e];
  const int m0 = blockIdx.x * 256;
  if (m0 >= ce) return;
  const int by = blockIdx.y;  // 0..15: wcat rows 256*by.. (=gate/up cols 128*by..128*by+127)

  __shared__ __align__(16) ushort smem[65536];  // 128 KB: A at 0, B at 32768 (ushort idx)
  __shared__ int rowinfo[256];

  const int tid = threadIdx.x;
  if (tid < 256) {
    int slot = m0 + tid;
    rowinfo[tid] = lists[e * T_TOK + (slot < ce ? slot : 0)];
  }
  __syncthreads();

  const int ww = tid >> 6, lane = tid & 63;
  const int lr = lane >> 3;
  const int srccol = ((lane & 7) ^ lr) * 8;   // pre-swizzled global chunk (both-sides XOR, T2)
  const int fm = lane & 15, fq = lane >> 4;
  const int waveM = ww >> 2, waveN = ww & 3;

  const ushort* wcatE = wcat + (size_t)e * 4096 * 1024;
  const ushort* aGp[4]; const ushort* bGp[4];
  int sOff[4];
#pragma unroll
  for (int j = 0; j < 4; ++j) {
    int s = j * 8 + ww;        // slab 0..31 (8 rows each)
    int row = s * 8 + lr;      // 0..255
    aGp[j] = xb + (size_t)(rowinfo[row] >> 1) * DDIM + srccol;
    bGp[j] = wcatE + (size_t)(256 * by + row) * DDIM + srccol;
    sOff[j] = s * 512;         // ushort offset of slab within a tile buffer
  }

  f32x4 acc[8][4];
  const f32x4 zero4 = {0.f, 0.f, 0.f, 0.f};
#pragma unroll
  for (int i = 0; i < 8; ++i)
#pragma unroll
    for (int j = 0; j < 4; ++j) acc[i][j] = zero4;

  // prologue: stage tile 0 into dbuf 0, drain, barrier
#pragma unroll
  for (int j = 0; j < 4; ++j) {
    async_copy16(smem + sOff[j], aGp[j]);
    async_copy16(smem + 32768 + sOff[j], bGp[j]);
  }
  asm volatile("s_waitcnt vmcnt(0)" ::: "memory");
  __builtin_amdgcn_s_barrier();
  asm volatile("" ::: "memory");

#pragma unroll 1
  for (int t = 0; t < 16; ++t) {
    const int d = (t & 1) * 16384;
    const int dn = ((t + 1) & 1) * 16384;
    const ushort* As = smem + d;
    const ushort* Bs = smem + 32768 + d;
    bf16x8 af[4][2], b0[2][2], b1[2][2];

    // ---- phase 1: read A(mh=0)+B(nh=0); issue stage of tile t+1; MFMA quadrant (0,0)
#pragma unroll
    for (int i = 0; i < 4; ++i) {
      int row = waveM * 128 + i * 16 + fm;
#pragma unroll
      for (int ks = 0; ks < 2; ++ks)
        af[i][ks] = *(const bf16x8*)&As[row * 64 + (((ks * 4 + fq) ^ (fm & 7)) * 8)];
    }
#pragma unroll
    for (int n = 0; n < 2; ++n) {
      int brow = waveN * 64 + n * 16 + fm;
#pragma unroll
      for (int ks = 0; ks < 2; ++ks)
        b0[n][ks] = *(const bf16x8*)&Bs[brow * 64 + (((ks * 4 + fq) ^ (fm & 7)) * 8)];
    }
    if (t + 1 < 16) {
#pragma unroll
      for (int j = 0; j < 4; ++j) {
        async_copy16(smem + dn + sOff[j], aGp[j] + (t + 1) * 64);
        async_copy16(smem + 32768 + dn + sOff[j], bGp[j] + (t + 1) * 64);
      }
    }
    __builtin_amdgcn_s_barrier();
    asm volatile("" ::: "memory");
    __builtin_amdgcn_s_setprio(1);
#pragma unroll
    for (int i = 0; i < 4; ++i)
#pragma unroll
      for (int n = 0; n < 2; ++n)
#pragma unroll
        for (int ks = 0; ks < 2; ++ks)
          acc[i][n] = __builtin_amdgcn_mfma_f32_16x16x32_bf16(af[i][ks], b0[n][ks], acc[i][n], 0, 0, 0);
    __builtin_amdgcn_s_setprio(0);
    __builtin_amdgcn_s_barrier();
    asm volatile("" ::: "memory");

    // ---- phase 2: read B(nh=1); MFMA quadrant (0,1)
#pragma unroll
    for (int n = 0; n < 2; ++n) {
      int brow = waveN * 64 + (2 + n) * 16 + fm;
#pragma unroll
      for (int ks = 0; ks < 2; ++ks)
        b1[n][ks] = *(const bf16x8*)&Bs[brow * 64 + (((ks * 4 + fq) ^ (fm & 7)) * 8)];
    }
    __builtin_amdgcn_s_barrier();
    asm volatile("" ::: "memory");
    __builtin_amdgcn_s_setprio(1);
#pragma unroll
    for (int i = 0; i < 4; ++i)
#pragma unroll
      for (int n = 0; n < 2; ++n)
#pragma unroll
        for (int ks = 0; ks < 2; ++ks)
          acc[i][2 + n] = __builtin_amdgcn_mfma_f32_16x16x32_bf16(af[i][ks], b1[n][ks], acc[i][2 + n], 0, 0, 0);
    __builtin_amdgcn_s_setprio(0);
    __builtin_amdgcn_s_barrier();
    asm volatile("" ::: "memory");

    // ---- phase 3: read A(mh=1) (overwrite af); MFMA quadrant (1,1) with b1
#pragma unroll
    for (int i = 0; i < 4; ++i) {
      int row = waveM * 128 + (4 + i) * 16 + fm;
#pragma unroll
      for (int ks = 0; ks < 2; ++ks)
        af[i][ks] = *(const bf16x8*)&As[row * 64 + (((ks * 4 + fq) ^ (fm & 7)) * 8)];
    }
    __builtin_amdgcn_s_barrier();
    asm volatile("" ::: "memory");
    __builtin_amdgcn_s_setprio(1);
#pragma unroll
    for (int i = 0; i < 4; ++i)
#pragma unroll
      for (int n = 0; n < 2; ++n)
#pragma unroll
        for (int ks = 0; ks < 2; ++ks)
          acc[4 + i][2 + n] = __builtin_amdgcn_mfma_f32_16x16x32_bf16(af[i][ks], b1[n][ks], acc[4 + i][2 + n], 0, 0, 0);
    __builtin_amdgcn_s_setprio(0);
    __builtin_amdgcn_s_barrier();
    asm volatile("" ::: "memory");

    // ---- phase 4: MFMA quadrant (1,0) with b0 (no new reads); drain stage; tile boundary
    __builtin_amdgcn_s_setprio(1);
#pragma unroll
    for (int i = 0; i < 4; ++i)
#pragma unroll
      for (int n = 0; n < 2; ++n)
#pragma unroll
        for (int ks = 0; ks < 2; ++ks)
          acc[4 + i][n] = __builtin_amdgcn_mfma_f32_16x16x32_bf16(af[i][ks], b0[n][ks], acc[4 + i][n], 0, 0, 0);
    __builtin_amdgcn_s_setprio(0);
    asm volatile("s_waitcnt vmcnt(0)" ::: "memory");  // tile t+1 fully resident
    __builtin_amdgcn_s_barrier();
    asm volatile("" ::: "memory");
  }

  // ---- epilogue: up-waves (waveN odd) publish to LDS; gate-waves fuse silu(g)*u
  __syncthreads();
  float* uld = (float*)smem;  // 32768 floats = 4 regions x 8192
  const int pair = waveN >> 1;
  const int base = (pair * 2 + waveM) * 8192;
  if (waveN & 1) {
#pragma unroll
    for (int mf = 0; mf < 8; ++mf)
#pragma unroll
      for (int nf = 0; nf < 4; ++nf)
#pragma unroll
        for (int r = 0; r < 4; ++r)
          uld[base + (mf * 16 + fq * 4 + r) * 64 + nf * 16 + fm] = acc[mf][nf][r];
  }
  __syncthreads();
  if (!(waveN & 1)) {
#pragma unroll
    for (int mf = 0; mf < 8; ++mf) {
#pragma unroll
      for (int r = 0; r < 4; ++r) {
        const int row = waveM * 128 + mf * 16 + fq * 4 + r;
        if (m0 + row < ce) {
          const int packed = rowinfo[row];
#pragma unroll
          for (int nf = 0; nf < 4; ++nf) {
            const int col = 128 * by + pair * 64 + nf * 16 + fm;
            float g = acc[mf][nf][r] + gate_b[e * IDIM + col];
            float u = uld[base + (mf * 16 + fq * 4 + r) * 64 + nf * 16 + fm] + up_b[e * IDIM + col];
            float h = g * (1.f / (1.f + __expf(-g))) * u;
            hbuf[(size_t)packed * IDIM + col] = f2bf(h);
          }
        }
      }
    }
  }
}

// ---------------- GEMM2: cbuf[pair] = h @ down_w (R0-proven structure, 128x128, BK=64) ----------------
__global__ __launch_bounds__(256, 2) void gemm2_kernel(
    const ushort* __restrict__ hbuf, const ushort* __restrict__ downT,
    const int* __restrict__ lists, const int* __restrict__ cnt,
    ushort* __restrict__ cbuf) {
  const int e = blockIdx.z;
  const int ce = cnt[e];
  const int m0 = blockIdx.x * 128;
  if (m0 >= ce) return;
  const int by = blockIdx.y;  // 0..7 -> cols 128*by..

  __shared__ __align__(16) ushort smem[2 * 128 * 64];
  __shared__ int rowinfo[128];
  ushort* As = smem;
  ushort* Bs = smem + 128 * 64;

  const int tid = threadIdx.x;
  if (tid < 128) {
    int slot = m0 + tid;
    rowinfo[tid] = lists[e * T_TOK + (slot < ce ? slot : 0)];
  }
  __syncthreads();

  const int w = tid >> 6, lane = tid & 63;
  const int fm = lane & 15, fq = lane >> 4;
  const int waveM = w >> 1, waveN = w & 1;
  const int lr = lane >> 3;
  const int lchunk = ((lane & 7) ^ lr) * 8;

  const ushort* downE = downT + (size_t)e * DDIM * IDIM;
  const ushort* aG[4]; const ushort* bG[4];
  ushort* aL[4]; ushort* bL[4];
#pragma unroll
  for (int j = 0; j < 4; ++j) {
    int rl = 32 * w + 8 * j + lr;
    aG[j] = hbuf + (size_t)rowinfo[rl] * IDIM + lchunk;
    bG[j] = downE + (size_t)(128 * by + rl) * IDIM + lchunk;
    aL[j] = As + (32 * w + 8 * j) * 64;
    bL[j] = Bs + (32 * w + 8 * j) * 64;
  }

  f32x4 acc[4][4];
  const f32x4 zero4 = {0.f, 0.f, 0.f, 0.f};
#pragma unroll
  for (int i = 0; i < 4; ++i)
#pragma unroll
    for (int j = 0; j < 4; ++j) acc[i][j] = zero4;

#pragma unroll 1
  for (int kt = 0; kt < IDIM / 64; ++kt) {
    __syncthreads();
#pragma unroll
    for (int j = 0; j < 4; ++j) {
      async_copy16(aL[j], aG[j] + kt * 64);
      async_copy16(bL[j], bG[j] + kt * 64);
    }
    __syncthreads();
#pragma unroll
    for (int ks = 0; ks < 2; ++ks) {
      bf16x8 af[4], bfr[4];
#pragma unroll
      for (int mf = 0; mf < 4; ++mf) {
        int row = 64 * waveM + 16 * mf + fm;
        af[mf] = *(const bf16x8*)&As[row * 64 + (((ks * 4 + fq) ^ (fm & 7)) * 8)];
      }
#pragma unroll
      for (int nf = 0; nf < 4; ++nf) {
        int row = 64 * waveN + 16 * nf + fm;
        bfr[nf] = *(const bf16x8*)&Bs[row * 64 + (((ks * 4 + fq) ^ (fm & 7)) * 8)];
      }
#pragma unroll
      for (int mf = 0; mf < 4; ++mf)
#pragma unroll
        for (int nf = 0; nf < 4; ++nf)
          acc[mf][nf] = __builtin_amdgcn_mfma_f32_16x16x32_bf16(af[mf], bfr[nf], acc[mf][nf], 0, 0, 0);
    }
  }

#pragma unroll
  for (int mf = 0; mf < 4; ++mf) {
#pragma unroll
    for (int r = 0; r < 4; ++r) {
      const int row = 64 * waveM + 16 * mf + 4 * fq + r;
      if (m0 + row < ce) {
        const int packed = rowinfo[row];
        ushort* crow = cbuf + (size_t)packed * DDIM + 128 * by + 64 * waveN;
#pragma unroll
        for (int nf = 0; nf < 4; ++nf)
          crow[16 * nf + fm] = f2bf(acc[mf][nf][r]);
      }
    }
  }
}

// ---------------- combine: out[t] = w0*(c0+db[e0]) + w1*(c1+db[e1]) ----------------
__global__ __launch_bounds__(256) void combine_kernel(
    const ushort* __restrict__ cbuf, const float* __restrict__ down_b,
    const int* __restrict__ pexp, const float* __restrict__ wts,
    float* __restrict__ out) {
  const int i = blockIdx.x * 256 + threadIdx.x;  // one thread per 8 cols
  const int token = i >> 7;                      // DDIM/8 = 128 segs
  const int seg = (i & 127) * 8;
  const float w0 = wts[token * 2], w1 = wts[token * 2 + 1];
  const int e0 = pexp[token * 2], e1 = pexp[token * 2 + 1];
  const ushort* c0 = cbuf + (size_t)(token * 2) * DDIM + seg;
  const ushort* c1 = c0 + DDIM;
  const float* b0 = down_b + e0 * DDIM + seg;
  const float* b1 = down_b + e1 * DDIM + seg;
  ushort4 v0a = ((const ushort4*)c0)[0], v0b = ((const ushort4*)c0)[1];
  ushort4 v1a = ((const ushort4*)c1)[0], v1b = ((const ushort4*)c1)[1];
  float4 ba0 = ((const float4*)b0)[0], bb0 = ((const float4*)b0)[1];
  float4 ba1 = ((const float4*)b1)[0], bb1 = ((const float4*)b1)[1];
  float4 o0, o1;
  o0.x = w0 * (bf2f(v0a.x) + ba0.x) + w1 * (bf2f(v1a.x) + ba1.x);
  o0.y = w0 * (bf2f(v0a.y) + ba0.y) + w1 * (bf2f(v1a.y) + ba1.y);
  o0.z = w0 * (bf2f(v0a.z) + ba0.z) + w1 * (bf2f(v1a.z) + ba1.z);
  o0.w = w0 * (bf2f(v0a.w) + ba0.w) + w1 * (bf2f(v1a.w) + ba1.w);
  o1.x = w0 * (bf2f(v0b.x) + bb0.x) + w1 * (bf2f(v1b.x) + bb1.x);
  o1.y = w0 * (bf2f(v0b.y) + bb0.y) + w1 * (bf2f(v1b.y) + bb1.y);
  o1.z = w0 * (bf2f(v0b.z) + bb0.z) + w1 * (bf2f(v1b.z) + bb1.z);
  o1.w = w0 * (bf2f(v0b.w) + bb0.w) + w1 * (bf2f(v1b.w) + bb1.w);
  float* op = out + (size_t)token * DDIM + seg;
  ((float4*)op)[0] = o0;
  ((float4*)op)[1] = o1;
}

extern "C" void kernel_launch(void* const* d_in, const int* in_sizes, int n_in,
                              void* d_out, int out_size, void* d_ws, size_t ws_size,
                              hipStream_t stream) {
  const float* x = (const float*)d_in[0];
  const float* rw = (const float*)d_in[1];
  const float* rb = (const float*)d_in[2];
  const float* gw = (const float*)d_in[3];
  const float* gb = (const float*)d_in[4];
  const float* uw = (const float*)d_in[5];
  const float* ub = (const float*)d_in[6];
  const float* dw = (const float*)d_in[7];
  const float* db = (const float*)d_in[8];
  float* out = (float*)d_out;

  char* ws = (char*)d_ws;
  ushort* xb    = (ushort*)(ws);                              // 16 MB
  ushort* hbuf  = (ushort*)(ws + (16ull << 20));              // 64 MB
  ushort* wcat  = (ushort*)(ws + (80ull << 20));              // 64 MB (dead after gemm1)
  ushort* cbuf  = wcat;                                       // 32 MB, aliases wcat
  ushort* downT = (ushort*)(ws + (144ull << 20));             // 32 MB
  float*  wts   = (float*) (ws + (176ull << 20));             // 64 KB
  int*    lists = (int*)   (ws + (176ull << 20) + 65536);     // 256 KB
  int*    cnt   = (int*)   (ws + (176ull << 20) + 65536 + 262144);
  int*    pexp  = (int*)   (ws + (176ull << 20) + 65536 + 262144 + 4096);  // 64 KB

  hipMemsetAsync(cnt, 0, NEXP * sizeof(int), stream);

  convert_kernel<<<(T_TOK * DDIM / 4 + 255) / 256, 256, 0, stream>>>(x, xb, T_TOK * DDIM / 4);
  router_kernel<<<T_TOK / 4, 256, 0, stream>>>(x, rw, rb, cnt, lists, wts, pexp);
  tconv_kernel<<<dim3(IDIM / 64, DDIM / 64, NEXP), 256, 0, stream>>>(
      gw, wcat, DDIM, IDIM, 0, 1, (size_t)DDIM * IDIM, (size_t)2 * IDIM * DDIM);
  tconv_kernel<<<dim3(IDIM / 64, DDIM / 64, NEXP), 256, 0, stream>>>(
      uw, wcat, DDIM, IDIM, 1, 1, (size_t)DDIM * IDIM, (size_t)2 * IDIM * DDIM);
  tconv_kernel<<<dim3(DDIM / 64, IDIM / 64, NEXP), 256, 0, stream>>>(
      dw, downT, IDIM, DDIM, 0, 0, (size_t)IDIM * DDIM, (size_t)DDIM * IDIM);

  gemm1_kernel<<<dim3(T_TOK / 256, IDIM * 2 / 256, NEXP), 512, 0, stream>>>(
      xb, wcat, gb, ub, lists, cnt, hbuf);
  gemm2_kernel<<<dim3(T_TOK / 128, DDIM / 128, NEXP), 256, 0, stream>>>(
      hbuf, downT, lists, cnt, cbuf);
  combine_kernel<<<T_TOK * DDIM / 8 / 256, 256, 0, stream>>>(cbuf, db, pexp, wts, out);
}

// Round 5
// 731.762 us; speedup vs baseline: 1.7318x; 1.7318x over previous
//
#include <hip/hip_runtime.h>

#define T_TOK 8192
#define DDIM 1024
#define IDIM 2048
#define NEXP 8

typedef short bf16x8 __attribute__((ext_vector_type(8)));
typedef float f32x4 __attribute__((ext_vector_type(4)));

__device__ __forceinline__ unsigned short f2bf(float f) {
  union { float f; unsigned int u; } v; v.f = f;
  unsigned int r = v.u + 0x7fffu + ((v.u >> 16) & 1u);
  return (unsigned short)(r >> 16);
}
__device__ __forceinline__ float bf2f(unsigned short u) {
  union { unsigned int u; float f; } v; v.u = (unsigned int)u << 16;
  return v.f;
}

typedef const __attribute__((address_space(1))) void* gas_t;
typedef __attribute__((address_space(3))) void* las_t;
__device__ __forceinline__ void async_copy16(void* lds, const void* g) {
  __builtin_amdgcn_global_load_lds((gas_t)g, (las_t)lds, 16, 0, 0);
}

// ---------------- x -> bf16 ----------------
__global__ __launch_bounds__(256) void convert_kernel(const float* __restrict__ x,
                                                      ushort* __restrict__ xb, int n4) {
  int i = blockIdx.x * 256 + threadIdx.x;
  if (i >= n4) return;
  float4 v = ((const float4*)x)[i];
  ushort4 o;
  o.x = f2bf(v.x); o.y = f2bf(v.y); o.z = f2bf(v.z); o.w = f2bf(v.w);
  ((ushort4*)xb)[i] = o;
}

// ---------------- transpose + convert via LDS: src[e][R][C] f32 -> dst[e][C'][R] bf16 ----------------
__global__ __launch_bounds__(256) void tconv_kernel(
    const float* __restrict__ src, ushort* __restrict__ dst, int R, int C,
    int sel, int interleave, size_t srcEStride, size_t dstEStride) {
  __shared__ ushort lt[64 * 72];
  const int e = blockIdx.z;
  const float* s = src + (size_t)e * srcEStride;
  ushort* d = dst + (size_t)e * dstEStride;
  const int c0 = blockIdx.x * 64, r0 = blockIdx.y * 64;
  const int t = threadIdx.x;
  const int tr = t >> 2;
  const int tc = (t & 3) * 16;
  const float* sp = s + (size_t)(r0 + tr) * C + c0 + tc;
  float4 v0 = ((const float4*)sp)[0];
  float4 v1 = ((const float4*)sp)[1];
  float4 v2 = ((const float4*)sp)[2];
  float4 v3 = ((const float4*)sp)[3];
#pragma unroll
  for (int j = 0; j < 4; ++j) lt[(tc + j) * 72 + tr]      = f2bf(((const float*)&v0)[j]);
#pragma unroll
  for (int j = 0; j < 4; ++j) lt[(tc + 4 + j) * 72 + tr]  = f2bf(((const float*)&v1)[j]);
#pragma unroll
  for (int j = 0; j < 4; ++j) lt[(tc + 8 + j) * 72 + tr]  = f2bf(((const float*)&v2)[j]);
#pragma unroll
  for (int j = 0; j < 4; ++j) lt[(tc + 12 + j) * 72 + tr] = f2bf(((const float*)&v3)[j]);
  __syncthreads();
  const int cr = t >> 2;
  const int seg = (t & 3) * 16;
  const int ci = c0 + cr;
  const int drow = interleave ? ((ci >> 6) * 128 + sel * 64 + (ci & 63)) : ci;
  uint4 o0 = *(const uint4*)&lt[cr * 72 + seg];
  uint4 o1 = *(const uint4*)&lt[cr * 72 + seg + 8];
  ushort* dp = d + (size_t)drow * R + r0 + seg;
  *(uint4*)dp = o0;
  *(uint4*)(dp + 8) = o1;
}

// ---------------- router: top-2 + expert lists ----------------
__global__ __launch_bounds__(256) void router_kernel(
    const float* __restrict__ x, const float* __restrict__ rw, const float* __restrict__ rb,
    int* __restrict__ cnt, int* __restrict__ lists, float* __restrict__ wts,
    int* __restrict__ pexp) {
  const int token = blockIdx.x * 4 + (threadIdx.x >> 6);
  const int lane = threadIdx.x & 63;
  float acc[NEXP];
#pragma unroll
  for (int e = 0; e < NEXP; ++e) acc[e] = 0.f;
  const float* xr = x + (size_t)token * DDIM;
#pragma unroll
  for (int j = 0; j < DDIM / 64; ++j) {
    int d = j * 64 + lane;
    float xv = xr[d];
    const float4* w = (const float4*)(rw + d * NEXP);
    float4 w0 = w[0], w1 = w[1];
    acc[0] += xv * w0.x; acc[1] += xv * w0.y; acc[2] += xv * w0.z; acc[3] += xv * w0.w;
    acc[4] += xv * w1.x; acc[5] += xv * w1.y; acc[6] += xv * w1.z; acc[7] += xv * w1.w;
  }
#pragma unroll
  for (int e = 0; e < NEXP; ++e) {
    float v = acc[e];
    for (int off = 32; off > 0; off >>= 1) v += __shfl_xor(v, off, 64);
    acc[e] = v;
  }
  if (lane == 0) {
    float l[NEXP];
#pragma unroll
    for (int e = 0; e < NEXP; ++e) l[e] = acc[e] + rb[e];
    int i0 = 0; float b0 = l[0];
#pragma unroll
    for (int e = 1; e < NEXP; ++e) if (l[e] > b0) { b0 = l[e]; i0 = e; }
    int i1 = -1; float b1 = -3.0e38f;
#pragma unroll
    for (int e = 0; e < NEXP; ++e) if (e != i0 && l[e] > b1) { b1 = l[e]; i1 = e; }
    float e1 = expf(b1 - b0);
    float inv = 1.f / (1.f + e1);
    wts[token * 2 + 0] = inv;
    wts[token * 2 + 1] = e1 * inv;
    pexp[token * 2 + 0] = i0;
    pexp[token * 2 + 1] = i1;
    int s0 = atomicAdd(&cnt[i0], 1);
    lists[i0 * T_TOK + s0] = token * 2;
    int s1 = atomicAdd(&cnt[i1], 1);
    lists[i1 * T_TOK + s1] = token * 2 + 1;
  }
}

// ---------------- GEMM1: fused gate/up, R0-proven structure + XCD-chunked block swizzle ----------------
// Swizzle: physical flat p -> logical l = (p&7)*chunk + p>>3 (bijective, nwg=2048 divisible by 8).
// Logical decomposed m0-fastest: XCD k owns contiguous m0-runs for the same by -> B-tile becomes
// L2-resident per XCD (16 active m0-blocks hit it); consecutive by-groups re-hit A via L3.
__global__ __launch_bounds__(256, 2) void gemm1_kernel(
    const ushort* __restrict__ xb, const ushort* __restrict__ wcat,
    const float* __restrict__ gate_b, const float* __restrict__ up_b,
    const int* __restrict__ lists, const int* __restrict__ cnt,
    ushort* __restrict__ hbuf) {
  const int e = blockIdx.z;
  const int ce = cnt[e];
  // grid: x = 64 (m0 slots), y = 32 (by). nwg = 2048, chunk = 256.
  const int p = blockIdx.x + (blockIdx.y << 6);
  const int l = (p & 7) * 256 + (p >> 3);
  const int m0 = (l & 63) * 128;
  const int by = l >> 6;  // 0..31 -> cols 64*by..+63 (gate & up)
  if (m0 >= ce) return;

  __shared__ __align__(16) ushort smem[2 * 128 * 64];  // As | Bs, 32 KB
  __shared__ int rowinfo[128];
  ushort* As = smem;
  ushort* Bs = smem + 128 * 64;

  const int tid = threadIdx.x;
  if (tid < 128) {
    int slot = m0 + tid;
    rowinfo[tid] = lists[e * T_TOK + (slot < ce ? slot : 0)];
  }
  __syncthreads();

  const int w = tid >> 6, lane = tid & 63;
  const int fm = lane & 15, fq = lane >> 4;
  const int waveM = w >> 1, waveN = w & 1;
  const int lr = lane >> 3;
  const int lchunk = ((lane & 7) ^ lr) * 8;

  const ushort* wcatE = wcat + (size_t)e * 4096 * 1024;
  const ushort* aG[4]; const ushort* bG[4];
  ushort* aL[4]; ushort* bL[4];
#pragma unroll
  for (int j = 0; j < 4; ++j) {
    int rl = 32 * w + 8 * j + lr;
    aG[j] = xb + (size_t)(rowinfo[rl] >> 1) * DDIM + lchunk;
    bG[j] = wcatE + (size_t)(128 * by + rl) * DDIM + lchunk;
    aL[j] = As + (32 * w + 8 * j) * 64;
    bL[j] = Bs + (32 * w + 8 * j) * 64;
  }

  f32x4 acc[4][4];
  const f32x4 zero4 = {0.f, 0.f, 0.f, 0.f};
#pragma unroll
  for (int i = 0; i < 4; ++i)
#pragma unroll
    for (int j = 0; j < 4; ++j) acc[i][j] = zero4;

#pragma unroll 1
  for (int kt = 0; kt < DDIM / 64; ++kt) {
    __syncthreads();
#pragma unroll
    for (int j = 0; j < 4; ++j) {
      async_copy16(aL[j], aG[j] + kt * 64);
      async_copy16(bL[j], bG[j] + kt * 64);
    }
    __syncthreads();
#pragma unroll
    for (int ks = 0; ks < 2; ++ks) {
      bf16x8 af[4], bfr[4];
#pragma unroll
      for (int mf = 0; mf < 4; ++mf) {
        int row = 64 * waveM + 16 * mf + fm;
        af[mf] = *(const bf16x8*)&As[row * 64 + (((ks * 4 + fq) ^ (fm & 7)) * 8)];
      }
#pragma unroll
      for (int nf = 0; nf < 4; ++nf) {
        int row = 64 * waveN + 16 * nf + fm;
        bfr[nf] = *(const bf16x8*)&Bs[row * 64 + (((ks * 4 + fq) ^ (fm & 7)) * 8)];
      }
#pragma unroll
      for (int mf = 0; mf < 4; ++mf)
#pragma unroll
        for (int nf = 0; nf < 4; ++nf)
          acc[mf][nf] = __builtin_amdgcn_mfma_f32_16x16x32_bf16(af[mf], bfr[nf], acc[mf][nf], 0, 0, 0);
    }
  }

  // epilogue: up-waves publish u via LDS; gate-waves fuse silu(g)*u
  __syncthreads();
  float* uld = (float*)smem;  // [128][64] fp32 = 32 KB
  if (waveN == 1) {
#pragma unroll
    for (int mf = 0; mf < 4; ++mf)
#pragma unroll
      for (int nf = 0; nf < 4; ++nf)
#pragma unroll
        for (int r = 0; r < 4; ++r)
          uld[(64 * waveM + 16 * mf + 4 * fq + r) * 64 + 16 * nf + fm] = acc[mf][nf][r];
  }
  __syncthreads();
  if (waveN == 0) {
#pragma unroll
    for (int mf = 0; mf < 4; ++mf) {
#pragma unroll
      for (int r = 0; r < 4; ++r) {
        const int row = 64 * waveM + 16 * mf + 4 * fq + r;
        if (m0 + row < ce) {
          const int packed = rowinfo[row];
#pragma unroll
          for (int nf = 0; nf < 4; ++nf) {
            const int col = 64 * by + 16 * nf + fm;
            float g = acc[mf][nf][r] + gate_b[e * IDIM + col];
            float u = uld[row * 64 + 16 * nf + fm] + up_b[e * IDIM + col];
            float h = g * (1.f / (1.f + __expf(-g))) * u;
            hbuf[(size_t)packed * IDIM + col] = f2bf(h);
          }
        }
      }
    }
  }
}

// ---------------- GEMM2: cbuf[pair] = h @ down_w, R0 structure + XCD-chunked swizzle ----------------
__global__ __launch_bounds__(256, 2) void gemm2_kernel(
    const ushort* __restrict__ hbuf, const ushort* __restrict__ downT,
    const int* __restrict__ lists, const int* __restrict__ cnt,
    ushort* __restrict__ cbuf) {
  const int e = blockIdx.z;
  const int ce = cnt[e];
  // grid: x = 64 (m0 slots), y = 8 (by). nwg = 512, chunk = 64.
  const int p = blockIdx.x + (blockIdx.y << 6);
  const int l = (p & 7) * 64 + (p >> 3);
  const int m0 = (l & 63) * 128;
  const int by = l >> 6;  // 0..7 -> cols 128*by..
  if (m0 >= ce) return;

  __shared__ __align__(16) ushort smem[2 * 128 * 64];
  __shared__ int rowinfo[128];
  ushort* As = smem;
  ushort* Bs = smem + 128 * 64;

  const int tid = threadIdx.x;
  if (tid < 128) {
    int slot = m0 + tid;
    rowinfo[tid] = lists[e * T_TOK + (slot < ce ? slot : 0)];
  }
  __syncthreads();

  const int w = tid >> 6, lane = tid & 63;
  const int fm = lane & 15, fq = lane >> 4;
  const int waveM = w >> 1, waveN = w & 1;
  const int lr = lane >> 3;
  const int lchunk = ((lane & 7) ^ lr) * 8;

  const ushort* downE = downT + (size_t)e * DDIM * IDIM;
  const ushort* aG[4]; const ushort* bG[4];
  ushort* aL[4]; ushort* bL[4];
#pragma unroll
  for (int j = 0; j < 4; ++j) {
    int rl = 32 * w + 8 * j + lr;
    aG[j] = hbuf + (size_t)rowinfo[rl] * IDIM + lchunk;
    bG[j] = downE + (size_t)(128 * by + rl) * IDIM + lchunk;
    aL[j] = As + (32 * w + 8 * j) * 64;
    bL[j] = Bs + (32 * w + 8 * j) * 64;
  }

  f32x4 acc[4][4];
  const f32x4 zero4 = {0.f, 0.f, 0.f, 0.f};
#pragma unroll
  for (int i = 0; i < 4; ++i)
#pragma unroll
    for (int j = 0; j < 4; ++j) acc[i][j] = zero4;

#pragma unroll 1
  for (int kt = 0; kt < IDIM / 64; ++kt) {
    __syncthreads();
#pragma unroll
    for (int j = 0; j < 4; ++j) {
      async_copy16(aL[j], aG[j] + kt * 64);
      async_copy16(bL[j], bG[j] + kt * 64);
    }
    __syncthreads();
#pragma unroll
    for (int ks = 0; ks < 2; ++ks) {
      bf16x8 af[4], bfr[4];
#pragma unroll
      for (int mf = 0; mf < 4; ++mf) {
        int row = 64 * waveM + 16 * mf + fm;
        af[mf] = *(const bf16x8*)&As[row * 64 + (((ks * 4 + fq) ^ (fm & 7)) * 8)];
      }
#pragma unroll
      for (int nf = 0; nf < 4; ++nf) {
        int row = 64 * waveN + 16 * nf + fm;
        bfr[nf] = *(const bf16x8*)&Bs[row * 64 + (((ks * 4 + fq) ^ (fm & 7)) * 8)];
      }
#pragma unroll
      for (int mf = 0; mf < 4; ++mf)
#pragma unroll
        for (int nf = 0; nf < 4; ++nf)
          acc[mf][nf] = __builtin_amdgcn_mfma_f32_16x16x32_bf16(af[mf], bfr[nf], acc[mf][nf], 0, 0, 0);
    }
  }

#pragma unroll
  for (int mf = 0; mf < 4; ++mf) {
#pragma unroll
    for (int r = 0; r < 4; ++r) {
      const int row = 64 * waveM + 16 * mf + 4 * fq + r;
      if (m0 + row < ce) {
        const int packed = rowinfo[row];
        ushort* crow = cbuf + (size_t)packed * DDIM + 128 * by + 64 * waveN;
#pragma unroll
        for (int nf = 0; nf < 4; ++nf)
          crow[16 * nf + fm] = f2bf(acc[mf][nf][r]);
      }
    }
  }
}

// ---------------- combine: out[t] = w0*(c0+db[e0]) + w1*(c1+db[e1]) ----------------
__global__ __launch_bounds__(256) void combine_kernel(
    const ushort* __restrict__ cbuf, const float* __restrict__ down_b,
    const int* __restrict__ pexp, const float* __restrict__ wts,
    float* __restrict__ out) {
  const int i = blockIdx.x * 256 + threadIdx.x;  // one thread per 8 cols
  const int token = i >> 7;                      // DDIM/8 = 128 segs
  const int seg = (i & 127) * 8;
  const float w0 = wts[token * 2], w1 = wts[token * 2 + 1];
  const int e0 = pexp[token * 2], e1 = pexp[token * 2 + 1];
  const ushort* c0 = cbuf + (size_t)(token * 2) * DDIM + seg;
  const ushort* c1 = c0 + DDIM;
  const float* b0 = down_b + e0 * DDIM + seg;
  const float* b1 = down_b + e1 * DDIM + seg;
  ushort4 v0a = ((const ushort4*)c0)[0], v0b = ((const ushort4*)c0)[1];
  ushort4 v1a = ((const ushort4*)c1)[0], v1b = ((const ushort4*)c1)[1];
  float4 ba0 = ((const float4*)b0)[0], bb0 = ((const float4*)b0)[1];
  float4 ba1 = ((const float4*)b1)[0], bb1 = ((const float4*)b1)[1];
  float4 o0, o1;
  o0.x = w0 * (bf2f(v0a.x) + ba0.x) + w1 * (bf2f(v1a.x) + ba1.x);
  o0.y = w0 * (bf2f(v0a.y) + ba0.y) + w1 * (bf2f(v1a.y) + ba1.y);
  o0.z = w0 * (bf2f(v0a.z) + ba0.z) + w1 * (bf2f(v1a.z) + ba1.z);
  o0.w = w0 * (bf2f(v0a.w) + ba0.w) + w1 * (bf2f(v1a.w) + ba1.w);
  o1.x = w0 * (bf2f(v0b.x) + bb0.x) + w1 * (bf2f(v1b.x) + bb1.x);
  o1.y = w0 * (bf2f(v0b.y) + bb0.y) + w1 * (bf2f(v1b.y) + bb1.y);
  o1.z = w0 * (bf2f(v0b.z) + bb0.z) + w1 * (bf2f(v1b.z) + bb1.z);
  o1.w = w0 * (bf2f(v0b.w) + bb0.w) + w1 * (bf2f(v1b.w) + bb1.w);
  float* op = out + (size_t)token * DDIM + seg;
  ((float4*)op)[0] = o0;
  ((float4*)op)[1] = o1;
}

extern "C" void kernel_launch(void* const* d_in, const int* in_sizes, int n_in,
                              void* d_out, int out_size, void* d_ws, size_t ws_size,
                              hipStream_t stream) {
  const float* x = (const float*)d_in[0];
  const float* rw = (const float*)d_in[1];
  const float* rb = (const float*)d_in[2];
  const float* gw = (const float*)d_in[3];
  const float* gb = (const float*)d_in[4];
  const float* uw = (const float*)d_in[5];
  const float* ub = (const float*)d_in[6];
  const float* dw = (const float*)d_in[7];
  const float* db = (const float*)d_in[8];
  float* out = (float*)d_out;

  char* ws = (char*)d_ws;
  ushort* xb    = (ushort*)(ws);                              // 16 MB
  ushort* hbuf  = (ushort*)(ws + (16ull << 20));              // 64 MB
  ushort* wcat  = (ushort*)(ws + (80ull << 20));              // 64 MB (dead after gemm1)
  ushort* cbuf  = wcat;                                       // 32 MB, aliases wcat
  ushort* downT = (ushort*)(ws + (144ull << 20));             // 32 MB
  float*  wts   = (float*) (ws + (176ull << 20));             // 64 KB
  int*    lists = (int*)   (ws + (176ull << 20) + 65536);     // 256 KB
  int*    cnt   = (int*)   (ws + (176ull << 20) + 65536 + 262144);
  int*    pexp  = (int*)   (ws + (176ull << 20) + 65536 + 262144 + 4096);  // 64 KB

  hipMemsetAsync(cnt, 0, NEXP * sizeof(int), stream);

  convert_kernel<<<(T_TOK * DDIM / 4 + 255) / 256, 256, 0, stream>>>(x, xb, T_TOK * DDIM / 4);
  router_kernel<<<T_TOK / 4, 256, 0, stream>>>(x, rw, rb, cnt, lists, wts, pexp);
  tconv_kernel<<<dim3(IDIM / 64, DDIM / 64, NEXP), 256, 0, stream>>>(
      gw, wcat, DDIM, IDIM, 0, 1, (size_t)DDIM * IDIM, (size_t)2 * IDIM * DDIM);
  tconv_kernel<<<dim3(IDIM / 64, DDIM / 64, NEXP), 256, 0, stream>>>(
      uw, wcat, DDIM, IDIM, 1, 1, (size_t)DDIM * IDIM, (size_t)2 * IDIM * DDIM);
  tconv_kernel<<<dim3(DDIM / 64, IDIM / 64, NEXP), 256, 0, stream>>>(
      dw, downT, IDIM, DDIM, 0, 0, (size_t)IDIM * DDIM, (size_t)DDIM * IDIM);

  gemm1_kernel<<<dim3(T_TOK / 128, IDIM / 64, NEXP), 256, 0, stream>>>(
      xb, wcat, gb, ub, lists, cnt, hbuf);
  gemm2_kernel<<<dim3(T_TOK / 128, DDIM / 128, NEXP), 256, 0, stream>>>(
      hbuf, downT, lists, cnt, cbuf);
  combine_kernel<<<T_TOK * DDIM / 8 / 256, 256, 0, stream>>>(cbuf, db, pexp, wts, out);
}

// Round 6
// 578.052 us; speedup vs baseline: 2.1923x; 1.2659x over previous
//
#include <hip/hip_runtime.h>

#define T_TOK 8192
#define DDIM 1024
#define IDIM 2048
#define NEXP 8

typedef short bf16x8 __attribute__((ext_vector_type(8)));
typedef float f32x4 __attribute__((ext_vector_type(4)));

__device__ __forceinline__ unsigned short f2bf(float f) {
  union { float f; unsigned int u; } v; v.f = f;
  unsigned int r = v.u + 0x7fffu + ((v.u >> 16) & 1u);
  return (unsigned short)(r >> 16);
}
__device__ __forceinline__ float bf2f(unsigned short u) {
  union { unsigned int u; float f; } v; v.u = (unsigned int)u << 16;
  return v.f;
}

typedef const __attribute__((address_space(1))) void* gas_t;
typedef __attribute__((address_space(3))) void* las_t;
__device__ __forceinline__ void async_copy16(void* lds, const void* g) {
  __builtin_amdgcn_global_load_lds((gas_t)g, (las_t)lds, 16, 0, 0);
}

// ---------------- x -> bf16 ----------------
__global__ __launch_bounds__(256) void convert_kernel(const float* __restrict__ x,
                                                      ushort* __restrict__ xb, int n4) {
  int i = blockIdx.x * 256 + threadIdx.x;
  if (i >= n4) return;
  float4 v = ((const float4*)x)[i];
  ushort4 o;
  o.x = f2bf(v.x); o.y = f2bf(v.y); o.z = f2bf(v.z); o.w = f2bf(v.w);
  ((ushort4*)xb)[i] = o;
}

// ---------------- transpose + convert via LDS: src[e][R][C] f32 -> dst[e][C'][R] bf16 ----------------
__global__ __launch_bounds__(256) void tconv_kernel(
    const float* __restrict__ src, ushort* __restrict__ dst, int R, int C,
    int sel, int interleave, size_t srcEStride, size_t dstEStride) {
  __shared__ ushort lt[64 * 72];
  const int e = blockIdx.z;
  const float* s = src + (size_t)e * srcEStride;
  ushort* d = dst + (size_t)e * dstEStride;
  const int c0 = blockIdx.x * 64, r0 = blockIdx.y * 64;
  const int t = threadIdx.x;
  const int tr = t >> 2;
  const int tc = (t & 3) * 16;
  const float* sp = s + (size_t)(r0 + tr) * C + c0 + tc;
  float4 v0 = ((const float4*)sp)[0];
  float4 v1 = ((const float4*)sp)[1];
  float4 v2 = ((const float4*)sp)[2];
  float4 v3 = ((const float4*)sp)[3];
#pragma unroll
  for (int j = 0; j < 4; ++j) lt[(tc + j) * 72 + tr]      = f2bf(((const float*)&v0)[j]);
#pragma unroll
  for (int j = 0; j < 4; ++j) lt[(tc + 4 + j) * 72 + tr]  = f2bf(((const float*)&v1)[j]);
#pragma unroll
  for (int j = 0; j < 4; ++j) lt[(tc + 8 + j) * 72 + tr]  = f2bf(((const float*)&v2)[j]);
#pragma unroll
  for (int j = 0; j < 4; ++j) lt[(tc + 12 + j) * 72 + tr] = f2bf(((const float*)&v3)[j]);
  __syncthreads();
  const int cr = t >> 2;
  const int seg = (t & 3) * 16;
  const int ci = c0 + cr;
  const int drow = interleave ? ((ci >> 6) * 128 + sel * 64 + (ci & 63)) : ci;
  uint4 o0 = *(const uint4*)&lt[cr * 72 + seg];
  uint4 o1 = *(const uint4*)&lt[cr * 72 + seg + 8];
  ushort* dp = d + (size_t)drow * R + r0 + seg;
  *(uint4*)dp = o0;
  *(uint4*)(dp + 8) = o1;
}

// ---------------- router: top-2 + expert lists, block-aggregated atomics ----------------
// 128 blocks x 64 tokens (4 waves, 16 tokens/wave). Per-token LDS-atomic local position,
// 8 global atomics per block (1024 total vs 16384 per-token) -> removes L2 same-address
// atomic serialization (~12ns/op measured R5: 195us for 16K ops).
__global__ __launch_bounds__(256) void router_kernel(
    const float* __restrict__ x, const float* __restrict__ rw, const float* __restrict__ rb,
    int* __restrict__ cnt, int* __restrict__ lists, float* __restrict__ wts,
    int* __restrict__ pexp) {
  __shared__ int tokE[128];   // expert id per local entry (64 tokens x 2)
  __shared__ int loc[128];    // position within block for that expert
  __shared__ int hist[NEXP];
  __shared__ int base[NEXP];
  const int tid = threadIdx.x;
  const int w = tid >> 6, lane = tid & 63;
  if (tid < NEXP) hist[tid] = 0;
  __syncthreads();

#pragma unroll 1
  for (int tt = 0; tt < 16; ++tt) {
    const int token = blockIdx.x * 64 + w * 16 + tt;
    float acc[NEXP];
#pragma unroll
    for (int e = 0; e < NEXP; ++e) acc[e] = 0.f;
    const float* xr = x + (size_t)token * DDIM;
#pragma unroll
    for (int j = 0; j < DDIM / 64; ++j) {
      int d = j * 64 + lane;
      float xv = xr[d];
      const float4* wp = (const float4*)(rw + d * NEXP);
      float4 w0 = wp[0], w1 = wp[1];
      acc[0] += xv * w0.x; acc[1] += xv * w0.y; acc[2] += xv * w0.z; acc[3] += xv * w0.w;
      acc[4] += xv * w1.x; acc[5] += xv * w1.y; acc[6] += xv * w1.z; acc[7] += xv * w1.w;
    }
#pragma unroll
    for (int e = 0; e < NEXP; ++e) {
      float v = acc[e];
      for (int off = 32; off > 0; off >>= 1) v += __shfl_xor(v, off, 64);
      acc[e] = v;
    }
    if (lane == 0) {
      float l[NEXP];
#pragma unroll
      for (int e = 0; e < NEXP; ++e) l[e] = acc[e] + rb[e];
      int i0 = 0; float b0 = l[0];
#pragma unroll
      for (int e = 1; e < NEXP; ++e) if (l[e] > b0) { b0 = l[e]; i0 = e; }
      int i1 = -1; float b1 = -3.0e38f;
#pragma unroll
      for (int e = 0; e < NEXP; ++e) if (e != i0 && l[e] > b1) { b1 = l[e]; i1 = e; }
      float e1 = expf(b1 - b0);
      float inv = 1.f / (1.f + e1);
      wts[token * 2 + 0] = inv;
      wts[token * 2 + 1] = e1 * inv;
      pexp[token * 2 + 0] = i0;
      pexp[token * 2 + 1] = i1;
      const int k = (w * 16 + tt) * 2;
      tokE[k] = i0;
      tokE[k + 1] = i1;
      loc[k] = atomicAdd(&hist[i0], 1);
      loc[k + 1] = atomicAdd(&hist[i1], 1);
    }
  }
  __syncthreads();
  if (tid < NEXP) base[tid] = atomicAdd(&cnt[tid], hist[tid]);
  __syncthreads();
  if (tid < 128) {
    const int e = tokE[tid];
    const int token = blockIdx.x * 64 + (tid >> 1);
    lists[e * T_TOK + base[e] + loc[tid]] = token * 2 + (tid & 1);
  }
}

// ---------------- GEMM1: fused gate/up, R0-proven structure + XCD-chunked block swizzle ----------------
// Swizzle: physical flat p -> logical l = (p&7)*chunk + p>>3 (bijective, nwg=2048 divisible by 8).
// Logical decomposed m0-fastest: XCD k owns contiguous m0-runs for the same by -> B-tile becomes
// L2-resident per XCD (16 active m0-blocks hit it); consecutive by-groups re-hit A via L3.
__global__ __launch_bounds__(256, 2) void gemm1_kernel(
    const ushort* __restrict__ xb, const ushort* __restrict__ wcat,
    const float* __restrict__ gate_b, const float* __restrict__ up_b,
    const int* __restrict__ lists, const int* __restrict__ cnt,
    ushort* __restrict__ hbuf) {
  const int e = blockIdx.z;
  const int ce = cnt[e];
  // grid: x = 64 (m0 slots), y = 32 (by). nwg = 2048, chunk = 256.
  const int p = blockIdx.x + (blockIdx.y << 6);
  const int l = (p & 7) * 256 + (p >> 3);
  const int m0 = (l & 63) * 128;
  const int by = l >> 6;  // 0..31 -> cols 64*by..+63 (gate & up)
  if (m0 >= ce) return;

  __shared__ __align__(16) ushort smem[2 * 128 * 64];  // As | Bs, 32 KB
  __shared__ int rowinfo[128];
  ushort* As = smem;
  ushort* Bs = smem + 128 * 64;

  const int tid = threadIdx.x;
  if (tid < 128) {
    int slot = m0 + tid;
    rowinfo[tid] = lists[e * T_TOK + (slot < ce ? slot : 0)];
  }
  __syncthreads();

  const int w = tid >> 6, lane = tid & 63;
  const int fm = lane & 15, fq = lane >> 4;
  const int waveM = w >> 1, waveN = w & 1;
  const int lr = lane >> 3;
  const int lchunk = ((lane & 7) ^ lr) * 8;

  const ushort* wcatE = wcat + (size_t)e * 4096 * 1024;
  const ushort* aG[4]; const ushort* bG[4];
  ushort* aL[4]; ushort* bL[4];
#pragma unroll
  for (int j = 0; j < 4; ++j) {
    int rl = 32 * w + 8 * j + lr;
    aG[j] = xb + (size_t)(rowinfo[rl] >> 1) * DDIM + lchunk;
    bG[j] = wcatE + (size_t)(128 * by + rl) * DDIM + lchunk;
    aL[j] = As + (32 * w + 8 * j) * 64;
    bL[j] = Bs + (32 * w + 8 * j) * 64;
  }

  f32x4 acc[4][4];
  const f32x4 zero4 = {0.f, 0.f, 0.f, 0.f};
#pragma unroll
  for (int i = 0; i < 4; ++i)
#pragma unroll
    for (int j = 0; j < 4; ++j) acc[i][j] = zero4;

#pragma unroll 1
  for (int kt = 0; kt < DDIM / 64; ++kt) {
    __syncthreads();
#pragma unroll
    for (int j = 0; j < 4; ++j) {
      async_copy16(aL[j], aG[j] + kt * 64);
      async_copy16(bL[j], bG[j] + kt * 64);
    }
    __syncthreads();
#pragma unroll
    for (int ks = 0; ks < 2; ++ks) {
      bf16x8 af[4], bfr[4];
#pragma unroll
      for (int mf = 0; mf < 4; ++mf) {
        int row = 64 * waveM + 16 * mf + fm;
        af[mf] = *(const bf16x8*)&As[row * 64 + (((ks * 4 + fq) ^ (fm & 7)) * 8)];
      }
#pragma unroll
      for (int nf = 0; nf < 4; ++nf) {
        int row = 64 * waveN + 16 * nf + fm;
        bfr[nf] = *(const bf16x8*)&Bs[row * 64 + (((ks * 4 + fq) ^ (fm & 7)) * 8)];
      }
#pragma unroll
      for (int mf = 0; mf < 4; ++mf)
#pragma unroll
        for (int nf = 0; nf < 4; ++nf)
          acc[mf][nf] = __builtin_amdgcn_mfma_f32_16x16x32_bf16(af[mf], bfr[nf], acc[mf][nf], 0, 0, 0);
    }
  }

  // epilogue: up-waves publish u via LDS; gate-waves fuse silu(g)*u
  __syncthreads();
  float* uld = (float*)smem;  // [128][64] fp32 = 32 KB
  if (waveN == 1) {
#pragma unroll
    for (int mf = 0; mf < 4; ++mf)
#pragma unroll
      for (int nf = 0; nf < 4; ++nf)
#pragma unroll
        for (int r = 0; r < 4; ++r)
          uld[(64 * waveM + 16 * mf + 4 * fq + r) * 64 + 16 * nf + fm] = acc[mf][nf][r];
  }
  __syncthreads();
  if (waveN == 0) {
#pragma unroll
    for (int mf = 0; mf < 4; ++mf) {
#pragma unroll
      for (int r = 0; r < 4; ++r) {
        const int row = 64 * waveM + 16 * mf + 4 * fq + r;
        if (m0 + row < ce) {
          const int packed = rowinfo[row];
#pragma unroll
          for (int nf = 0; nf < 4; ++nf) {
            const int col = 64 * by + 16 * nf + fm;
            float g = acc[mf][nf][r] + gate_b[e * IDIM + col];
            float u = uld[row * 64 + 16 * nf + fm] + up_b[e * IDIM + col];
            float h = g * (1.f / (1.f + __expf(-g))) * u;
            hbuf[(size_t)packed * IDIM + col] = f2bf(h);
          }
        }
      }
    }
  }
}

// ---------------- GEMM2: cbuf[pair] = h @ down_w, R0 structure + XCD-chunked swizzle ----------------
__global__ __launch_bounds__(256, 2) void gemm2_kernel(
    const ushort* __restrict__ hbuf, const ushort* __restrict__ downT,
    const int* __restrict__ lists, const int* __restrict__ cnt,
    ushort* __restrict__ cbuf) {
  const int e = blockIdx.z;
  const int ce = cnt[e];
  // grid: x = 64 (m0 slots), y = 8 (by). nwg = 512, chunk = 64.
  const int p = blockIdx.x + (blockIdx.y << 6);
  const int l = (p & 7) * 64 + (p >> 3);
  const int m0 = (l & 63) * 128;
  const int by = l >> 6;  // 0..7 -> cols 128*by..
  if (m0 >= ce) return;

  __shared__ __align__(16) ushort smem[2 * 128 * 64];
  __shared__ int rowinfo[128];
  ushort* As = smem;
  ushort* Bs = smem + 128 * 64;

  const int tid = threadIdx.x;
  if (tid < 128) {
    int slot = m0 + tid;
    rowinfo[tid] = lists[e * T_TOK + (slot < ce ? slot : 0)];
  }
  __syncthreads();

  const int w = tid >> 6, lane = tid & 63;
  const int fm = lane & 15, fq = lane >> 4;
  const int waveM = w >> 1, waveN = w & 1;
  const int lr = lane >> 3;
  const int lchunk = ((lane & 7) ^ lr) * 8;

  const ushort* downE = downT + (size_t)e * DDIM * IDIM;
  const ushort* aG[4]; const ushort* bG[4];
  ushort* aL[4]; ushort* bL[4];
#pragma unroll
  for (int j = 0; j < 4; ++j) {
    int rl = 32 * w + 8 * j + lr;
    aG[j] = hbuf + (size_t)rowinfo[rl] * IDIM + lchunk;
    bG[j] = downE + (size_t)(128 * by + rl) * IDIM + lchunk;
    aL[j] = As + (32 * w + 8 * j) * 64;
    bL[j] = Bs + (32 * w + 8 * j) * 64;
  }

  f32x4 acc[4][4];
  const f32x4 zero4 = {0.f, 0.f, 0.f, 0.f};
#pragma unroll
  for (int i = 0; i < 4; ++i)
#pragma unroll
    for (int j = 0; j < 4; ++j) acc[i][j] = zero4;

#pragma unroll 1
  for (int kt = 0; kt < IDIM / 64; ++kt) {
    __syncthreads();
#pragma unroll
    for (int j = 0; j < 4; ++j) {
      async_copy16(aL[j], aG[j] + kt * 64);
      async_copy16(bL[j], bG[j] + kt * 64);
    }
    __syncthreads();
#pragma unroll
    for (int ks = 0; ks < 2; ++ks) {
      bf16x8 af[4], bfr[4];
#pragma unroll
      for (int mf = 0; mf < 4; ++mf) {
        int row = 64 * waveM + 16 * mf + fm;
        af[mf] = *(const bf16x8*)&As[row * 64 + (((ks * 4 + fq) ^ (fm & 7)) * 8)];
      }
#pragma unroll
      for (int nf = 0; nf < 4; ++nf) {
        int row = 64 * waveN + 16 * nf + fm;
        bfr[nf] = *(const bf16x8*)&Bs[row * 64 + (((ks * 4 + fq) ^ (fm & 7)) * 8)];
      }
#pragma unroll
      for (int mf = 0; mf < 4; ++mf)
#pragma unroll
        for (int nf = 0; nf < 4; ++nf)
          acc[mf][nf] = __builtin_amdgcn_mfma_f32_16x16x32_bf16(af[mf], bfr[nf], acc[mf][nf], 0, 0, 0);
    }
  }

#pragma unroll
  for (int mf = 0; mf < 4; ++mf) {
#pragma unroll
    for (int r = 0; r < 4; ++r) {
      const int row = 64 * waveM + 16 * mf + 4 * fq + r;
      if (m0 + row < ce) {
        const int packed = rowinfo[row];
        ushort* crow = cbuf + (size_t)packed * DDIM + 128 * by + 64 * waveN;
#pragma unroll
        for (int nf = 0; nf < 4; ++nf)
          crow[16 * nf + fm] = f2bf(acc[mf][nf][r]);
      }
    }
  }
}

// ---------------- combine: out[t] = w0*(c0+db[e0]) + w1*(c1+db[e1]) ----------------
__global__ __launch_bounds__(256) void combine_kernel(
    const ushort* __restrict__ cbuf, const float* __restrict__ down_b,
    const int* __restrict__ pexp, const float* __restrict__ wts,
    float* __restrict__ out) {
  const int i = blockIdx.x * 256 + threadIdx.x;  // one thread per 8 cols
  const int token = i >> 7;                      // DDIM/8 = 128 segs
  const int seg = (i & 127) * 8;
  const float w0 = wts[token * 2], w1 = wts[token * 2 + 1];
  const int e0 = pexp[token * 2], e1 = pexp[token * 2 + 1];
  const ushort* c0 = cbuf + (size_t)(token * 2) * DDIM + seg;
  const ushort* c1 = c0 + DDIM;
  const float* b0 = down_b + e0 * DDIM + seg;
  const float* b1 = down_b + e1 * DDIM + seg;
  ushort4 v0a = ((const ushort4*)c0)[0], v0b = ((const ushort4*)c0)[1];
  ushort4 v1a = ((const ushort4*)c1)[0], v1b = ((const ushort4*)c1)[1];
  float4 ba0 = ((const float4*)b0)[0], bb0 = ((const float4*)b0)[1];
  float4 ba1 = ((const float4*)b1)[0], bb1 = ((const float4*)b1)[1];
  float4 o0, o1;
  o0.x = w0 * (bf2f(v0a.x) + ba0.x) + w1 * (bf2f(v1a.x) + ba1.x);
  o0.y = w0 * (bf2f(v0a.y) + ba0.y) + w1 * (bf2f(v1a.y) + ba1.y);
  o0.z = w0 * (bf2f(v0a.z) + ba0.z) + w1 * (bf2f(v1a.z) + ba1.z);
  o0.w = w0 * (bf2f(v0a.w) + ba0.w) + w1 * (bf2f(v1a.w) + ba1.w);
  o1.x = w0 * (bf2f(v0b.x) + bb0.x) + w1 * (bf2f(v1b.x) + bb1.x);
  o1.y = w0 * (bf2f(v0b.y) + bb0.y) + w1 * (bf2f(v1b.y) + bb1.y);
  o1.z = w0 * (bf2f(v0b.z) + bb0.z) + w1 * (bf2f(v1b.z) + bb1.z);
  o1.w = w0 * (bf2f(v0b.w) + bb0.w) + w1 * (bf2f(v1b.w) + bb1.w);
  float* op = out + (size_t)token * DDIM + seg;
  ((float4*)op)[0] = o0;
  ((float4*)op)[1] = o1;
}

extern "C" void kernel_launch(void* const* d_in, const int* in_sizes, int n_in,
                              void* d_out, int out_size, void* d_ws, size_t ws_size,
                              hipStream_t stream) {
  const float* x = (const float*)d_in[0];
  const float* rw = (const float*)d_in[1];
  const float* rb = (const float*)d_in[2];
  const float* gw = (const float*)d_in[3];
  const float* gb = (const float*)d_in[4];
  const float* uw = (const float*)d_in[5];
  const float* ub = (const float*)d_in[6];
  const float* dw = (const float*)d_in[7];
  const float* db = (const float*)d_in[8];
  float* out = (float*)d_out;

  char* ws = (char*)d_ws;
  ushort* xb    = (ushort*)(ws);                              // 16 MB
  ushort* hbuf  = (ushort*)(ws + (16ull << 20));              // 64 MB
  ushort* wcat  = (ushort*)(ws + (80ull << 20));              // 64 MB (dead after gemm1)
  ushort* cbuf  = wcat;                                       // 32 MB, aliases wcat
  ushort* downT = (ushort*)(ws + (144ull << 20));             // 32 MB
  float*  wts   = (float*) (ws + (176ull << 20));             // 64 KB
  int*    lists = (int*)   (ws + (176ull << 20) + 65536);     // 256 KB
  int*    cnt   = (int*)   (ws + (176ull << 20) + 65536 + 262144);
  int*    pexp  = (int*)   (ws + (176ull << 20) + 65536 + 262144 + 4096);  // 64 KB

  hipMemsetAsync(cnt, 0, NEXP * sizeof(int), stream);

  convert_kernel<<<(T_TOK * DDIM / 4 + 255) / 256, 256, 0, stream>>>(x, xb, T_TOK * DDIM / 4);
  router_kernel<<<T_TOK / 64, 256, 0, stream>>>(x, rw, rb, cnt, lists, wts, pexp);
  tconv_kernel<<<dim3(IDIM / 64, DDIM / 64, NEXP), 256, 0, stream>>>(
      gw, wcat, DDIM, IDIM, 0, 1, (size_t)DDIM * IDIM, (size_t)2 * IDIM * DDIM);
  tconv_kernel<<<dim3(IDIM / 64, DDIM / 64, NEXP), 256, 0, stream>>>(
      uw, wcat, DDIM, IDIM, 1, 1, (size_t)DDIM * IDIM, (size_t)2 * IDIM * DDIM);
  tconv_kernel<<<dim3(DDIM / 64, IDIM / 64, NEXP), 256, 0, stream>>>(
      dw, downT, IDIM, DDIM, 0, 0, (size_t)IDIM * DDIM, (size_t)DDIM * IDIM);

  gemm1_kernel<<<dim3(T_TOK / 128, IDIM / 64, NEXP), 256, 0, stream>>>(
      xb, wcat, gb, ub, lists, cnt, hbuf);
  gemm2_kernel<<<dim3(T_TOK / 128, DDIM / 128, NEXP), 256, 0, stream>>>(
      hbuf, downT, lists, cnt, cbuf);
  combine_kernel<<<T_TOK * DDIM / 8 / 256, 256, 0, stream>>>(cbuf, db, pexp, wts, out);
}